// Round 4
// baseline (301.121 us; speedup 1.0000x reference)
//
#include <hip/hip_runtime.h>
#include <hip/hip_fp16.h>

#define VIEWS 16
#define NN 256
#define DWS 131                     // dwords per LDS row (262 halves: cols -2..259)
#define ROWS 259                    // rows y=-1..257 (index = y+1)
#define LDS_DW (ROWS*DWS)           // 33,929 dwords = 135,716 B

template<int CTRL>
__device__ __forceinline__ float dpp_add(float x) {
    int t = __builtin_amdgcn_update_dpp(0, __float_as_int(x), CTRL, 0xF, 0xF, true);
    return x + __int_as_float(t);
}

__launch_bounds__(1024, 1)
__global__ void fp_kernel(const float* __restrict__ vol, float* __restrict__ out) {
    __shared__ uint32_t lds[LDS_DW];
    const int tid = threadIdx.x;
    const int z = blockIdx.x;

    // ---- zero LDS (borders must be 0) ----
    for (int i = tid; i < LDS_DW; i += 1024) lds[i] = 0u;
    __syncthreads();

    // ---- stage slice z as fp16 (dword = 2 adjacent-x halves) ----
    __half* ldsH = (__half*)lds;
    const float* sp = vol + (size_t)z * (NN * NN);
    #pragma unroll
    for (int i = 0; i < 16; ++i) {
        int e = i * 4096 + tid * 4;
        float4 v4 = *(const float4*)(sp + e);
        int row = (e >> 8) + 1;
        int col = (e & 255) + 2;               // even -> dword-aligned
        __half2* p = (__half2*)&ldsH[row * (2 * DWS) + col];
        p[0] = __halves2half2(__float2half_rn(v4.x), __float2half_rn(v4.y));
        p[1] = __halves2half2(__float2half_rn(v4.z), __float2half_rn(v4.w));
    }
    __syncthreads();

    // ---- compute: wave = view; lane = x (sum axis); loop over output y ----
    const int wave = tid >> 6;
    const int lane = tid & 63;
    const float ang = 0.017453292519943295f + (float)wave * 0.19634954084936207f;
    const float c = cosf(ang), s = sinf(ang);

    // shifted coords: u = ix + 2 in [1,258], v = iy + 1 in [0,257]
    // ix = c*(x+.5) - s*(y+.5) + 128(1-c+s) - .5
    // iy = s*(x+.5) + c*(y+.5) + 128(1-s-c) - .5
    float u[4], v[4];
    #pragma unroll
    for (int k = 0; k < 4; ++k) {
        float px = (float)(64 * k + lane) + 0.5f;
        u[k] = c * px + (-s * 0.5f + 128.0f * (1.0f - c + s) + 1.5f);
        v[k] = s * px + ( c * 0.5f + 128.0f * (1.0f - s - c) + 0.5f);
    }

    float oreg[4];
    #pragma unroll
    for (int j = 0; j < 4; ++j) {
        float o = 0.0f;
        for (int yl = 0; yl < 64; ++yl) {
            float a = 0.0f;
            #pragma unroll
            for (int k = 0; k < 4; ++k) {
                float uc = fminf(fmaxf(u[k], 1.0f), 258.0f);   // -> v_med3
                float vc = fminf(fmaxf(v[k], 0.0f), 257.0f);
                int x0 = (int)uc;
                int y0 = (int)vc;
                float wx = uc - (float)x0;
                float wy = vc - (float)y0;
                int d = y0 * DWS + (x0 >> 1);
                uint32_t rA0 = lds[d];
                uint32_t rA1 = lds[d + 1];
                uint32_t rB0 = lds[d + DWS];
                uint32_t rB1 = lds[d + DWS + 1];
                uint32_t sh = (uint32_t)(x0 & 1) << 4;
                uint32_t pa = __builtin_amdgcn_alignbit(rA1, rA0, sh);
                uint32_t pb = __builtin_amdgcn_alignbit(rB1, rB0, sh);
                float2 fa = __half22float2(*(__half2*)&pa);
                float2 fb = __half22float2(*(__half2*)&pb);
                float h0 = fmaf(wx, fa.y - fa.x, fa.x);
                float h1 = fmaf(wx, fb.y - fb.x, fb.x);
                a += fmaf(wy, h1 - h0, h0);
                u[k] -= s;    // advance to next y
                v[k] += c;
            }
            // full-wave sum on the VALU pipe (DPP butterfly + row broadcasts)
            a = dpp_add<0xB1>(a);    // xor 1  (quad_perm 1,0,3,2)
            a = dpp_add<0x4E>(a);    // xor 2  (quad_perm 2,3,0,1)
            a = dpp_add<0x141>(a);   // xor 4  (row_half_mirror)
            a = dpp_add<0x140>(a);   // xor 8  (row_mirror)
            a = dpp_add<0x142>(a);   // 16->32 (row_bcast15)
            a = dpp_add<0x143>(a);   // 32->64 (row_bcast31): lane63 = total
            float tot = __int_as_float(__builtin_amdgcn_readlane(__float_as_int(a), 63));
            o = (lane == yl) ? tot : o;
        }
        oreg[j] = o;
    }
    __syncthreads();

    // ---- transpose through LDS for coalesced float4 output ----
    float* lout = (float*)lds;   // 4096 floats
    #pragma unroll
    for (int j = 0; j < 4; ++j) {
        int y = 64 * j + lane;
        lout[y * VIEWS + wave] = oreg[j];
    }
    __syncthreads();
    float4 r = *(float4*)&lout[tid * 4];
    float4* o4 = (float4*)(out + (size_t)z * (NN * VIEWS));
    o4[tid] = r;
}

extern "C" void kernel_launch(void* const* d_in, const int* in_sizes, int n_in,
                              void* d_out, int out_size, void* d_ws, size_t ws_size,
                              hipStream_t stream) {
    const float* vol = (const float*)d_in[0];
    float* out = (float*)d_out;
    fp_kernel<<<NN, 1024, 0, stream>>>(vol, out);
}

// Round 6
// 235.484 us; speedup vs baseline: 1.2787x; 1.2787x over previous
//
#include <hip/hip_runtime.h>
#include <hip/hip_fp16.h>

#define VIEWS 16
#define NN 256
#define DWS 131                     // dwords per LDS row (262 halves: cols -2..259)
#define ROWS 259                    // rows y=-1..257 (index = y+1)
#define LDS_DW (ROWS*DWS)           // 33,929 dwords = 135,716 B

typedef __fp16 h2 __attribute__((ext_vector_type(2)));
union U32H2 { uint32_t u; h2 h; };

__device__ __forceinline__ float fract_f(float x) {
#if __has_builtin(__builtin_amdgcn_fractf)
    return __builtin_amdgcn_fractf(x);
#else
    return x - floorf(x);
#endif
}

__launch_bounds__(1024, 1)
__global__ void fp_kernel(const float* __restrict__ vol, float* __restrict__ out) {
    __shared__ uint32_t lds[LDS_DW];
    const int tid = threadIdx.x;
    const int z = blockIdx.x;

    // ---- zero LDS (borders must be 0) ----
    for (int i = tid; i < LDS_DW; i += 1024) lds[i] = 0u;
    __syncthreads();

    // ---- stage slice z as fp16 (dword = 2 adjacent-x halves) ----
    __half* ldsH = (__half*)lds;
    const float* sp = vol + (size_t)z * (NN * NN);
    #pragma unroll
    for (int i = 0; i < 16; ++i) {
        int e = i * 4096 + tid * 4;
        float4 v4 = *(const float4*)(sp + e);
        int row = (e >> 8) + 1;
        int col = (e & 255) + 2;               // even -> dword-aligned
        __half2* p = (__half2*)&ldsH[row * (2 * DWS) + col];
        p[0] = __halves2half2(__float2half_rn(v4.x), __float2half_rn(v4.y));
        p[1] = __halves2half2(__float2half_rn(v4.z), __float2half_rn(v4.w));
    }
    __syncthreads();

    // ---- compute: wave = view; lane owns 4 output rows y = lane + 64r ----
    const int wave = tid >> 6;
    const int lane = tid & 63;
    const float ang = 0.017453292519943295f + (float)wave * 0.19634954084936207f;
    const float c = cosf(ang), s = sinf(ang);

    // shifted coords: u = ix + 2 in [1,258], v = iy + 1 in [0,257]
    // ix = c*(x+.5) - s*py + 128(1-c+s) - .5 ; iy = s*(x+.5) + c*py + 128(1-s-c) - .5
    float bix[4], biy[4], acc[4];
    #pragma unroll
    for (int r = 0; r < 4; ++r) {
        float py = (float)(lane + 64 * r) + 0.5f;
        bix[r] = -s * py + 128.0f * (1.0f - c + s) + 1.5f + 0.5f * c;
        biy[r] =  c * py + 128.0f * (1.0f - s - c) + 0.5f + 0.5f * s;
        acc[r] = 0.0f;
    }

    float xf = 0.0f;
    #pragma unroll 2
    for (int x = 0; x < NN; ++x) {
        #pragma unroll
        for (int r = 0; r < 4; ++r) {
            float u = fmaf(c, xf, bix[r]);
            float v = fmaf(s, xf, biy[r]);
            u = fminf(fmaxf(u, 1.0f), 258.0f);     // -> v_med3
            v = fminf(fmaxf(v, 0.0f), 257.0f);
            int x0 = (int)u;
            int y0 = (int)v;
            float wx = fract_f(u);                 // v_fract_f32
            float wy = fract_f(v);
            h2 wxp = __builtin_amdgcn_cvt_pkrtz(1.0f - wx, wx);  // (1-wx, wx) packed
            int d = y0 * DWS + (x0 >> 1);
            uint32_t rA0 = lds[d];
            uint32_t rA1 = lds[d + 1];
            uint32_t rB0 = lds[d + DWS];
            uint32_t rB1 = lds[d + DWS + 1];
            // alignbit uses shift[4:0] only -> pass x0<<4 raw (bit4 = parity*16)
            uint32_t sh = (uint32_t)(x0 << 4);
            U32H2 pa, pb;
            pa.u = __builtin_amdgcn_alignbit(rA1, rA0, sh);  // halves (x0, x0+1), row y0
            pb.u = __builtin_amdgcn_alignbit(rB1, rB0, sh);  // row y0+1
            float a1 = __builtin_amdgcn_fdot2(wxp, pa.h, 0.0f, false);  // v_dot2_f32_f16
            float a2 = __builtin_amdgcn_fdot2(wxp, pb.h, 0.0f, false);
            acc[r] += fmaf(wy, a2 - a1, a1);
        }
        xf += 1.0f;
    }
    __syncthreads();

    // ---- transpose through LDS for coalesced float4 output ----
    float* lout = (float*)lds;   // 4096 floats
    #pragma unroll
    for (int r = 0; r < 4; ++r) {
        int y = 64 * r + lane;
        lout[y * VIEWS + wave] = acc[r];
    }
    __syncthreads();
    float4 v4 = *(float4*)&lout[tid * 4];
    float4* o4 = (float4*)(out + (size_t)z * (NN * VIEWS));
    o4[tid] = v4;
}

extern "C" void kernel_launch(void* const* d_in, const int* in_sizes, int n_in,
                              void* d_out, int out_size, void* d_ws, size_t ws_size,
                              hipStream_t stream) {
    const float* vol = (const float*)d_in[0];
    float* out = (float*)d_out;
    fp_kernel<<<NN, 1024, 0, stream>>>(vol, out);
}

// Round 7
// 178.777 us; speedup vs baseline: 1.6843x; 1.3172x over previous
//
#include <hip/hip_runtime.h>
#include <hip/hip_fp16.h>

#define VIEWS 16
#define NN 256
#define DWS 131                     // dwords per LDS row (262 halves: cols -2..259)
#define ROWS 259                    // rows y=-1..257 (index = y+1)
#define LDS_DW (ROWS*DWS)           // 33,929 dwords = 135,716 B

typedef __fp16 h2 __attribute__((ext_vector_type(2)));
union U32H2 { uint32_t u; h2 h; };

template<int CTRL>
__device__ __forceinline__ float dpp_add(float x) {
    int t = __builtin_amdgcn_update_dpp(0, __float_as_int(x), CTRL, 0xF, 0xF, true);
    return x + __int_as_float(t);
}

__device__ __forceinline__ float fract_f(float x) {
#if __has_builtin(__builtin_amdgcn_fractf)
    return __builtin_amdgcn_fractf(x);
#else
    return x - floorf(x);
#endif
}

// one x-step: 4 rays (r=0..3), accumulate row partials into acc[], return 4-ray sum
#define DO_STEP(PARTIAL) do {                                                  \
    PARTIAL = 0.f;                                                             \
    _Pragma("unroll")                                                          \
    for (int r = 0; r < 4; ++r) {                                              \
        float u = fmaf(c, xf, bix[r]);                                         \
        float v = fmaf(s, xf, biy[r]);                                         \
        u = fminf(fmaxf(u, 1.0f), 258.0f);   /* -> v_med3 */                   \
        v = fminf(fmaxf(v, 0.0f), 257.0f);                                     \
        int x0 = (int)u;                                                       \
        int y0 = (int)v;                                                       \
        float wx = fract_f(u);                                                 \
        float wy = fract_f(v);                                                 \
        h2 wxp = __builtin_amdgcn_cvt_pkrtz(1.0f - wx, wx);                    \
        int d = (y0 << 7) + (y0 << 1) + y0 + (x0 >> 1);  /* y0*131 + x0/2 */   \
        uint32_t rA0 = lds[d];                                                 \
        uint32_t rA1 = lds[d + 1];                                             \
        uint32_t rB0 = lds[d + DWS];                                           \
        uint32_t rB1 = lds[d + DWS + 1];                                       \
        uint32_t sh = (uint32_t)(x0 << 4);   /* alignbit uses bits[4:0] */     \
        U32H2 pa, pb;                                                          \
        pa.u = __builtin_amdgcn_alignbit(rA1, rA0, sh);                        \
        pb.u = __builtin_amdgcn_alignbit(rB1, rB0, sh);                        \
        float a1 = __builtin_amdgcn_fdot2(wxp, pa.h, 0.0f, false);             \
        float a2 = __builtin_amdgcn_fdot2(wxp, pb.h, 0.0f, false);             \
        float t = fmaf(wy, a2 - a1, a1);                                       \
        acc[r] += t;                                                           \
        PARTIAL += t;                                                          \
    }                                                                          \
    xf += 1.0f;                                                                \
} while (0)

#define BUTTERFLY(P) do {                                                      \
    P = dpp_add<0xB1>(P);    /* xor 1  */                                      \
    P = dpp_add<0x4E>(P);    /* xor 2  */                                      \
    P = dpp_add<0x141>(P);   /* row_half_mirror */                             \
    P = dpp_add<0x140>(P);   /* row_mirror */                                  \
    P = dpp_add<0x142>(P);   /* row_bcast15 */                                 \
    P = dpp_add<0x143>(P);   /* row_bcast31: lane63 = total */                 \
} while (0)

__launch_bounds__(1024, 1)
__global__ void fp_kernel(const float* __restrict__ vol, float* __restrict__ out) {
    __shared__ uint32_t lds[LDS_DW];
    const int tid = threadIdx.x;
    const int z = blockIdx.x;

    // ---- zero LDS (borders must be 0) ----
    for (int i = tid; i < LDS_DW; i += 1024) lds[i] = 0u;
    __syncthreads();

    // ---- stage slice z as fp16 (dword = 2 adjacent-x halves) ----
    __half* ldsH = (__half*)lds;
    const float* sp = vol + (size_t)z * (NN * NN);
    #pragma unroll
    for (int i = 0; i < 16; ++i) {
        int e = i * 4096 + tid * 4;
        float4 v4 = *(const float4*)(sp + e);
        int row = (e >> 8) + 1;
        int col = (e & 255) + 2;               // even -> dword-aligned
        __half2* p = (__half2*)&ldsH[row * (2 * DWS) + col];
        p[0] = __halves2half2(__float2half_rn(v4.x), __float2half_rn(v4.y));
        p[1] = __halves2half2(__float2half_rn(v4.z), __float2half_rn(v4.w));
    }
    __syncthreads();

    // ---- 90-degree view pairing: wave -> (pair k, step-half h) ----
    // view k   (angle a):      proj_k[y]   = row-sum over steps of field S_k
    // view k+8 (angle a+90):   proj_k8[y]  = column-sum of S_k at step 255-y
    const int wave = tid >> 6;
    const int lane = tid & 63;
    const int k = wave >> 1;
    const int h = wave & 1;
    const float ang = 0.017453292519943295f + (float)k * 0.19634954084936207f;
    const float c = cosf(ang), s = sinf(ang);

    // shifted coords: u = ix + 2 in [1,258], v = iy + 1 in [0,257]
    float bix[4], biy[4], acc[4];
    #pragma unroll
    for (int r = 0; r < 4; ++r) {
        float py = (float)(lane + 64 * r) + 0.5f;
        bix[r] = -s * py + 128.0f * (1.0f - c + s) + 1.5f + 0.5f * c;
        biy[r] =  c * py + 128.0f * (1.0f - s - c) + 0.5f + 0.5f * s;
        acc[r] = 0.0f;
    }
    // bases above include the +0.5 for step; xf = integer step value
    float xf = (float)(128 * h);

    float creg0 = 0.0f, creg1 = 0.0f;   // column sums: steps 128h+lane, 128h+64+lane
    #pragma unroll 2
    for (int i = 0; i < 64; ++i) {
        float partial; DO_STEP(partial);
        BUTTERFLY(partial);
        float tot = __int_as_float(__builtin_amdgcn_readlane(__float_as_int(partial), 63));
        creg0 = (lane == i) ? tot : creg0;
    }
    #pragma unroll 2
    for (int i = 0; i < 64; ++i) {
        float partial; DO_STEP(partial);
        BUTTERFLY(partial);
        float tot = __int_as_float(__builtin_amdgcn_readlane(__float_as_int(partial), 63));
        creg1 = (lane == i) ? tot : creg1;
    }

    __syncthreads();   // all taps done; safe to reuse LDS

    // ---- assemble [256 y][16 views] in LDS ----
    float* lout = (float*)lds;   // 4096 floats
    if (h == 0) {
        #pragma unroll
        for (int r = 0; r < 4; ++r)
            lout[(lane + 64 * r) * VIEWS + k] = acc[r];
    }
    {   // column results -> view k+8, y = 255 - x  (disjoint ranges per h)
        int ybase = 255 - 128 * h;
        lout[(ybase - lane) * VIEWS + (k + 8)] = creg0;
        lout[(ybase - 64 - lane) * VIEWS + (k + 8)] = creg1;
    }
    __syncthreads();
    if (h == 1) {
        #pragma unroll
        for (int r = 0; r < 4; ++r)
            lout[(lane + 64 * r) * VIEWS + k] += acc[r];
    }
    __syncthreads();

    float4 v4 = *(float4*)&lout[tid * 4];
    float4* o4 = (float4*)(out + (size_t)z * (NN * VIEWS));
    o4[tid] = v4;
}

extern "C" void kernel_launch(void* const* d_in, const int* in_sizes, int n_in,
                              void* d_out, int out_size, void* d_ws, size_t ws_size,
                              hipStream_t stream) {
    const float* vol = (const float*)d_in[0];
    float* out = (float*)d_out;
    fp_kernel<<<NN, 1024, 0, stream>>>(vol, out);
}